// Round 4
// baseline (454.744 us; speedup 1.0000x reference)
//
#include <hip/hip_runtime.h>

// QuadratureFunction: out[c,q] = sum_b local_dofs[c,b] * y[c,b,q]
// C = 500000, NB = 10, Q = 16.
//
// Layout: 4 lanes ("parts") per cell; part p computes out[c, 4p..4p+3] (float4).
// Gather phase is split across the 4 parts and shared via LDS:
//   part 0: 3 vertex dofs            -> ld[0..2]
//   part k (k=1..3): edge k-1        -> ld[3+2(k-1) .. 4+2(k-1)] (orientation flip in-reg)
//   part 1 additionally: face dof    -> ld[9]
// The 10 float4 y-loads are issued BEFORE the barrier so gather latency hides
// under the y stream (320 MB, the dominant traffic).

#define NBASIS 10
#define CPB 64          // cells per 256-thread block
#define LDSTRIDE 12     // pad 10 -> 12 (2-way bank aliasing is free)

__global__ __launch_bounds__(256) void quad_kernel(
    const float*  __restrict__ vertex_dofs,   // [V,1]
    const float*  __restrict__ edge_dofs,     // [E,2]
    const float*  __restrict__ face_dofs,     // [C,1]
    const float4* __restrict__ y4,            // [C,10,16] as float4[C*40]
    const int*    __restrict__ faces,         // [C,3]
    const int*    __restrict__ f2e,           // [C,3]
    const int*    __restrict__ orient,        // [C,3]
    float4*       __restrict__ out4,          // [C,16] as float4[C*4]
    int C)
{
    __shared__ float sld[CPB * LDSTRIDE];

    const int tid   = threadIdx.x;
    const int lcell = tid >> 2;                   // 0..63 within block
    const int part  = tid & 3;
    const int c     = blockIdx.x * CPB + lcell;
    const bool valid = (c < C);

    float4 v[NBASIS];
    if (valid) {
        // ---- issue the dominant y stream first (independent of LDS) ----
        const float4* yp = y4 + (size_t)c * (NBASIS * 4) + part;
        #pragma unroll
        for (int b = 0; b < NBASIS; ++b) {
            v[b] = yp[(size_t)b * 4];
        }

        // ---- split gather ----
        float* ld = &sld[lcell * LDSTRIDE];
        if (part == 0) {
            int f0 = faces[3 * c + 0];
            int f1 = faces[3 * c + 1];
            int f2 = faces[3 * c + 2];
            ld[0] = vertex_dofs[f0];
            ld[1] = vertex_dofs[f1];
            ld[2] = vertex_dofs[f2];
        } else {
            const int j = part - 1;               // edge 0..2
            int e = f2e[3 * c + j];
            int o = orient[3 * c + j];
            float2 ev = ((const float2*)edge_dofs)[e];
            ld[3 + 2 * j + 0] = o ? ev.x : ev.y;
            ld[3 + 2 * j + 1] = o ? ev.y : ev.x;
            if (part == 1) ld[9] = face_dofs[c];
        }
    }

    __syncthreads();

    if (valid) {
        const float* ld = &sld[lcell * LDSTRIDE];
        float4 acc = make_float4(0.f, 0.f, 0.f, 0.f);
        #pragma unroll
        for (int b = 0; b < NBASIS; ++b) {
            float w = ld[b];
            acc.x = fmaf(w, v[b].x, acc.x);
            acc.y = fmaf(w, v[b].y, acc.y);
            acc.z = fmaf(w, v[b].z, acc.z);
            acc.w = fmaf(w, v[b].w, acc.w);
        }
        out4[(size_t)c * 4 + part] = acc;
    }
}

extern "C" void kernel_launch(void* const* d_in, const int* in_sizes, int n_in,
                              void* d_out, int out_size, void* d_ws, size_t ws_size,
                              hipStream_t stream) {
    const float*  vertex_dofs = (const float*)d_in[0];
    const float*  edge_dofs   = (const float*)d_in[1];
    const float*  face_dofs   = (const float*)d_in[2];
    const float4* y4          = (const float4*)d_in[3];
    const int*    faces       = (const int*)d_in[4];
    const int*    f2e         = (const int*)d_in[5];
    const int*    orient      = (const int*)d_in[6];
    float4*       out4        = (float4*)d_out;

    const int C = in_sizes[2];                 // face_dofs has C*DF = C elements
    const int grid = (C + CPB - 1) / CPB;      // 64 cells per 256-thread block

    quad_kernel<<<grid, 256, 0, stream>>>(vertex_dofs, edge_dofs, face_dofs,
                                          y4, faces, f2e, orient, out4, C);
}